// Round 2
// baseline (37759.164 us; speedup 1.0000x reference)
//
#include <hip/hip_runtime.h>

#define BB 32
#define SS 64
#define TT 64
#define VV 32000
#define EE 512
#define HH 1024
#define G4 4096
#define CHUNK 256
#define PADW 258   // 258 % 32 == 2 -> only free 2-way LDS bank aliasing
#define GRID 256
#define BLK 512
#define FLTMAX 3.402823466e38f

struct Par {
  const int *src, *tgt, *tmask;
  const float *enc_embed, *dec_embed;
  const float *enc_wih0, *enc_whh0, *enc_b0;
  const float *enc_wih1, *enc_whh1, *enc_b1;
  const float *dec_wih0, *dec_whh0, *dec_b0;
  const float *dec_wih1, *dec_whh1, *dec_b1;
  const float *fc_w, *fc_b;
  float *out;
  float *P0, *P1, *hA, *cA, *hB, *cB, *xcur, *ys0, *amv, *xg0;
  int *ami;
  int *bcnt, *bgen;
  int use_xg0;
};

__device__ __forceinline__ float sigf(float x) { return 1.0f / (1.0f + expf(-x)); }

// grid barrier: agent-scope release/acquire; all 256 blocks co-resident (1/CU).
__device__ __forceinline__ void gbar(int* cnt, int* gen, int target) {
  __syncthreads();
  if (threadIdx.x == 0) {
    int prev = __hip_atomic_fetch_add(cnt, 1, __ATOMIC_ACQ_REL, __HIP_MEMORY_SCOPE_AGENT);
    if (prev == GRID - 1) {
      __hip_atomic_store(cnt, 0, __ATOMIC_RELAXED, __HIP_MEMORY_SCOPE_AGENT);
      __hip_atomic_store(gen, target, __ATOMIC_RELEASE, __HIP_MEMORY_SCOPE_AGENT);
    } else {
      while (__hip_atomic_load(gen, __ATOMIC_ACQUIRE, __HIP_MEMORY_SCOPE_AGENT) < target)
        __builtin_amdgcn_s_sleep(8);
    }
  }
  __syncthreads();
}

// ---- LDS staging of a 32 x 256 fp32 input chunk --------------------------
__device__ __forceinline__ void stage_plain(const float* __restrict__ in, int stride,
                                            float (*hs)[PADW]) {
  int sb = threadIdx.x >> 4, c0 = (threadIdx.x & 15) << 4;
  const float4* s4 = reinterpret_cast<const float4*>(in + (long)sb * stride + c0);
  float4 v0 = s4[0], v1 = s4[1], v2 = s4[2], v3 = s4[3];
  float* d = &hs[sb][c0];
  d[0]=v0.x; d[1]=v0.y; d[2]=v0.z; d[3]=v0.w;
  d[4]=v1.x; d[5]=v1.y; d[6]=v1.z; d[7]=v1.w;
  d[8]=v2.x; d[9]=v2.y; d[10]=v2.z; d[11]=v2.w;
  d[12]=v3.x; d[13]=v3.y; d[14]=v3.z; d[15]=v3.w;
}

// staging with inlined embedding lookup (row 0 -> zeros)
__device__ __forceinline__ void stage_embed(const int* __restrict__ src, int t,
                                            const float* __restrict__ tab, int col0,
                                            float (*hs)[PADW]) {
  int sb = threadIdx.x >> 4, c0 = (threadIdx.x & 15) << 4;
  int tok = src[sb * SS + t];
  float4 v0 = make_float4(0.f,0.f,0.f,0.f), v1 = v0, v2 = v0, v3 = v0;
  if (tok) {
    const float4* s4 = reinterpret_cast<const float4*>(tab + (long)tok * EE + col0 + c0);
    v0 = s4[0]; v1 = s4[1]; v2 = s4[2]; v3 = s4[3];
  }
  float* d = &hs[sb][c0];
  d[0]=v0.x; d[1]=v0.y; d[2]=v0.z; d[3]=v0.w;
  d[4]=v1.x; d[5]=v1.y; d[6]=v1.z; d[7]=v1.w;
  d[8]=v2.x; d[9]=v2.y; d[10]=v2.z; d[11]=v2.w;
  d[12]=v3.x; d[13]=v3.y; d[14]=v3.z; d[15]=v3.w;
}

// 128-j x 32-b x 256-k partial dot; lane=b, 8 j per lane, broadcast weight rows
__device__ __forceinline__ void dot128(const float* __restrict__ wbase, int wstride,
                                       int jb, const float (*hs)[PADW], float* acc) {
  int lane = threadIdx.x & 63, wid = threadIdx.x >> 6;
  int rb = lane & 31, hf = lane >> 5;
  int jbase = jb * 128 + wid * 16 + hf * 8;
  const float* wr[8];
#pragma unroll
  for (int q = 0; q < 8; ++q) wr[q] = wbase + (long)(jbase + q) * wstride;
#pragma unroll 2
  for (int kk = 0; kk < CHUNK; kk += 4) {
    float2 h01 = *reinterpret_cast<const float2*>(&hs[rb][kk]);
    float2 h23 = *reinterpret_cast<const float2*>(&hs[rb][kk + 2]);
#pragma unroll
    for (int q = 0; q < 8; ++q) {
      float4 w4 = *reinterpret_cast<const float4*>(wr[q] + kk);
      acc[q] += h01.x * w4.x + h01.y * w4.y + h23.x * w4.z + h23.y * w4.w;
    }
  }
}

__device__ __forceinline__ void write_p(float* __restrict__ pdst, int jb, const float* acc) {
  int lane = threadIdx.x & 63, wid = threadIdx.x >> 6;
  int rb = lane & 31, hf = lane >> 5;
  int jbase = jb * 128 + wid * 16 + hf * 8;
  float* dst = pdst + (long)rb * G4 + jbase;
#pragma unroll
  for (int q = 0; q < 8; ++q) dst[q] = acc[q];
}

__device__ __forceinline__ void gemm_tile_plain(const float* in, int instride,
    const float* wcol, int wstride, float* pdst, int jb, float (*hs)[PADW]) {
  __syncthreads();
  stage_plain(in, instride, hs);
  __syncthreads();
  float acc[8] = {0,0,0,0,0,0,0,0};
  dot128(wcol, wstride, jb, hs, acc);
  write_p(pdst, jb, acc);
}

__device__ __forceinline__ void gemm_tile_embed(const int* src, int t, const float* tab,
    int col0, const float* wcol, int wstride, float* pdst, int jb, float (*hs)[PADW]) {
  __syncthreads();
  stage_embed(src, t, tab, col0, hs);
  __syncthreads();
  float acc[8] = {0,0,0,0,0,0,0,0};
  dot128(wcol, wstride, jb, hs, acc);
  write_p(pdst, jb, acc);
}

// LSTM cell for one (b,u): bias + optional xg + nc partial chunks, then gates
__device__ __forceinline__ void cell_item(const float* __restrict__ P, int nc,
    const float* __restrict__ bias, const float* __restrict__ xg,
    float* __restrict__ h, float* __restrict__ c, float* __restrict__ ys, int i) {
  int b = i >> 10, u = i & (HH - 1);
  float gi = bias[u], gf = bias[HH + u], gg = bias[2*HH + u], go = bias[3*HH + u];
  if (xg) {
    const float* x = xg + (long)b * G4;
    gi += x[u]; gf += x[HH + u]; gg += x[2*HH + u]; go += x[3*HH + u];
  }
  for (int kc = 0; kc < nc; ++kc) {
    const float* pp = P + ((long)kc * BB + b) * G4;
    gi += pp[u]; gf += pp[HH + u]; gg += pp[2*HH + u]; go += pp[3*HH + u];
  }
  float cn = sigf(gf) * c[i] + sigf(gi) * tanhf(gg);
  float hn = sigf(go) * tanhf(cn);
  c[i] = cn; h[i] = hn;
  if (ys) ys[i] = hn;
}

__global__ __launch_bounds__(BLK) void mega(Par p) {
  __shared__ float hs[BB][PADW];
  __shared__ float av[16][BB];
  __shared__ int   ai[16][BB];
  int gen = 0;
  const int tid = threadIdx.x;
  const int bid = blockIdx.x;
  const int gid = bid * BLK + tid;

  // ---- init: states, out[:,0,:], xcur = dec_tab[tgt[:,0]]
  if (tid < 128) {
    int i = bid * 128 + tid;
    p.hA[i] = 0.f; p.cA[i] = 0.f; p.hB[i] = 0.f; p.cB[i] = 0.f;
  }
  if (gid < BB * EE) {
    int b = gid >> 9, e = gid & (EE - 1);
    int tok = p.tgt[b * TT];
    p.xcur[gid] = tok ? p.dec_embed[(long)tok * EE + e] : 0.f;
  }
  for (long g = gid; g < (long)BB * VV; g += (long)GRID * BLK) {
    int b = (int)(g / VV); int v = (int)(g - (long)b * VV);
    p.out[(long)b * TT * VV + v] = 0.f;
  }
  gbar(p.bcnt, p.bgen, ++gen);

  // ---- xg0[t][b][:] = xs[t] @ enc_wih0^T  (embedding inlined)
  if (p.use_xg0) {
    for (int tl = bid; tl < SS * 32; tl += GRID) {
      int t = tl >> 5, jb = tl & 31;
      float acc[8] = {0,0,0,0,0,0,0,0};
      for (int kc = 0; kc < 2; ++kc) {
        __syncthreads();
        stage_embed(p.src, t, p.enc_embed, kc * CHUNK, hs);
        __syncthreads();
        dot128(p.enc_wih0 + kc * CHUNK, EE, jb, hs, acc);
      }
      write_p(p.xg0 + (long)t * BB * G4, jb, acc);
    }
    gbar(p.bcnt, p.bgen, ++gen);
  }

  const int NC0 = p.use_xg0 ? 4 : 6;

  // ---- encoder: layer0(t) and layer1(t-1) pipelined per super-step
  for (int tt = 0; tt <= SS; ++tt) {
    int n0 = (tt < SS) ? NC0 * 32 : 0;
    int n1 = (tt >= 1) ? 8 * 32 : 0;
    for (int tl = bid; tl < n0 + n1; tl += GRID) {
      if (tl < n0) {
        int kc = tl >> 5, jb = tl & 31;
        float* pdst = p.P0 + (long)kc * BB * G4;
        if (p.use_xg0) {
          gemm_tile_plain(p.hA + kc * CHUNK, HH, p.enc_whh0 + kc * CHUNK, HH, pdst, jb, hs);
        } else {
          if (kc < 2)
            gemm_tile_embed(p.src, tt, p.enc_embed, kc * CHUNK,
                            p.enc_wih0 + kc * CHUNK, EE, pdst, jb, hs);
          else
            gemm_tile_plain(p.hA + (kc-2) * CHUNK, HH, p.enc_whh0 + (kc-2) * CHUNK, HH,
                            pdst, jb, hs);
        }
      } else {
        int u = tl - n0; int kc = u >> 5, jb = u & 31;
        float* pdst = p.P1 + (long)kc * BB * G4;
        const float* ys_t = p.ys0 + (long)(tt - 1) * BB * HH;
        if (kc < 4)
          gemm_tile_plain(ys_t + kc * CHUNK, HH, p.enc_wih1 + kc * CHUNK, HH, pdst, jb, hs);
        else
          gemm_tile_plain(p.hB + (kc-4) * CHUNK, HH, p.enc_whh1 + (kc-4) * CHUNK, HH,
                          pdst, jb, hs);
      }
    }
    gbar(p.bcnt, p.bgen, ++gen);
    if (tid < 128) {
      if (tt < SS)
        cell_item(p.P0, NC0, p.enc_b0,
                  p.use_xg0 ? p.xg0 + (long)tt * BB * G4 : nullptr,
                  p.hA, p.cA, p.ys0 + (long)tt * BB * HH, bid * 128 + tid);
    } else if (tid < 256) {
      if (tt >= 1)
        cell_item(p.P1, 8, p.enc_b1, nullptr, p.hB, p.cB, nullptr, bid * 128 + (tid - 128));
    }
    gbar(p.bcnt, p.bgen, ++gen);
  }

  // ---- decoder
  for (int k = 0; k < TT - 1; ++k) {
    int t = k + 1;
    // G0: gates0 partials (x: xcur 512 | h: hA 1024) -> P0[0..5]
    for (int tl = bid; tl < 6 * 32; tl += GRID) {
      int kc = tl >> 5, jb = tl & 31;
      float* pdst = p.P0 + (long)kc * BB * G4;
      if (kc < 2)
        gemm_tile_plain(p.xcur + kc * CHUNK, EE, p.dec_wih0 + kc * CHUNK, EE, pdst, jb, hs);
      else
        gemm_tile_plain(p.hA + (kc-2) * CHUNK, HH, p.dec_whh0 + (kc-2) * CHUNK, HH,
                        pdst, jb, hs);
    }
    gbar(p.bcnt, p.bgen, ++gen);
    if (tid < 128) cell_item(p.P0, 6, p.dec_b0, nullptr, p.hA, p.cA, nullptr, bid*128 + tid);
    gbar(p.bcnt, p.bgen, ++gen);
    // G1: gates1 partials (x: hA | h: hB) -> P1[0..7]
    for (int tl = bid; tl < 8 * 32; tl += GRID) {
      int kc = tl >> 5, jb = tl & 31;
      float* pdst = p.P1 + (long)kc * BB * G4;
      if (kc < 4)
        gemm_tile_plain(p.hA + kc * CHUNK, HH, p.dec_wih1 + kc * CHUNK, HH, pdst, jb, hs);
      else
        gemm_tile_plain(p.hB + (kc-4) * CHUNK, HH, p.dec_whh1 + (kc-4) * CHUNK, HH,
                        pdst, jb, hs);
    }
    gbar(p.bcnt, p.bgen, ++gen);
    if (tid < 128) cell_item(p.P1, 8, p.dec_b1, nullptr, p.hB, p.cB, nullptr, bid*128 + tid);
    gbar(p.bcnt, p.bgen, ++gen);
    // FC (full K=1024, 4 restagings) + logits write + per-tile argmax
    for (int tl = bid; tl < 250; tl += GRID) {
      float acc[8] = {0,0,0,0,0,0,0,0};
      for (int r = 0; r < 4; ++r) {
        __syncthreads();
        stage_plain(p.hB + r * CHUNK, HH, hs);
        __syncthreads();
        dot128(p.fc_w + r * CHUNK, HH, tl, hs, acc);
      }
      int lane = tid & 63, wid = tid >> 6, rb = lane & 31, hf = lane >> 5;
      int jbase = tl * 128 + wid * 16 + hf * 8;
      float bv = -FLTMAX; int bi = 0;
      float* dst = p.out + (long)rb * TT * VV + (long)t * VV + jbase;
#pragma unroll
      for (int q = 0; q < 8; ++q) {
        float v = acc[q] + p.fc_b[jbase + q];
        dst[q] = v;
        if (v > bv) { bv = v; bi = jbase + q; }
      }
      __syncthreads();
      av[wid * 2 + hf][rb] = bv; ai[wid * 2 + hf][rb] = bi;
      __syncthreads();
      if (tid < BB) {
        float v = av[0][tid]; int vi = ai[0][tid];
#pragma unroll
        for (int s = 1; s < 16; ++s) {
          float w = av[s][tid]; int wi = ai[s][tid];
          if (w > v || (w == v && wi < vi)) { v = w; vi = wi; }
        }
        p.amv[(long)tl * BB + tid] = v;
        p.ami[tl * BB + tid] = vi;
      }
    }
    gbar(p.bcnt, p.bgen, ++gen);
    // AM: reduce 250 tile-candidates per row, teacher select, embed next input
    {
      int gw = (bid << 3) + (tid >> 6);
      int lane = tid & 63;
      if (gw < BB) {
        int b = gw;
        float bv = -FLTMAX; int bi = 0x7fffffff;
        for (int s = lane; s < 250; s += 64) {
          float v = p.amv[(long)s * BB + b]; int i2 = p.ami[s * BB + b];
          if (v > bv || (v == bv && i2 < bi)) { bv = v; bi = i2; }
        }
        for (int off = 32; off > 0; off >>= 1) {
          float ov = __shfl_down(bv, off); int oi = __shfl_down(bi, off);
          if (ov > bv || (ov == bv && oi < bi)) { bv = ov; bi = oi; }
        }
        int tok = 0;
        if (lane == 0) tok = (p.tmask[t] > 0) ? p.tgt[b * TT + t] : bi;
        tok = __shfl(tok, 0);
        float4 z = make_float4(0.f,0.f,0.f,0.f);
        float4 v0 = z, v1 = z;
        if (tok) {
          const float4* s4 = reinterpret_cast<const float4*>(p.dec_embed + (long)tok * EE + lane * 8);
          v0 = s4[0]; v1 = s4[1];
        }
        float4* d = reinterpret_cast<float4*>(p.xcur + b * EE + lane * 8);
        d[0] = v0; d[1] = v1;
      }
    }
    gbar(p.bcnt, p.bgen, ++gen);
  }
}

extern "C" void kernel_launch(void* const* d_in, const int* in_sizes, int n_in,
                              void* d_out, int out_size, void* d_ws, size_t ws_size,
                              hipStream_t stream) {
  Par p;
  p.src       = (const int*)d_in[0];
  p.tgt       = (const int*)d_in[1];
  p.tmask     = (const int*)d_in[2];
  p.enc_embed = (const float*)d_in[3];
  p.dec_embed = (const float*)d_in[4];
  p.enc_wih0  = (const float*)d_in[5];
  p.enc_whh0  = (const float*)d_in[6];
  p.enc_b0    = (const float*)d_in[7];
  p.enc_wih1  = (const float*)d_in[8];
  p.enc_whh1  = (const float*)d_in[9];
  p.enc_b1    = (const float*)d_in[10];
  p.dec_wih0  = (const float*)d_in[11];
  p.dec_whh0  = (const float*)d_in[12];
  p.dec_b0    = (const float*)d_in[13];
  p.dec_wih1  = (const float*)d_in[14];
  p.dec_whh1  = (const float*)d_in[15];
  p.dec_b1    = (const float*)d_in[16];
  p.fc_w      = (const float*)d_in[17];
  p.fc_b      = (const float*)d_in[18];
  p.out       = (float*)d_out;

  p.bcnt = (int*)d_ws;                 // byte 0
  p.bgen = (int*)d_ws + 32;            // byte 128 (separate line)
  float* ws = (float*)((char*)d_ws + 256);
  size_t off = 0;
  p.P0   = ws + off; off += (size_t)8 * BB * G4;   // 1,048,576
  p.P1   = ws + off; off += (size_t)8 * BB * G4;   // 1,048,576
  p.hA   = ws + off; off += BB * HH;
  p.cA   = ws + off; off += BB * HH;
  p.hB   = ws + off; off += BB * HH;
  p.cB   = ws + off; off += BB * HH;
  p.xcur = ws + off; off += BB * EE;
  p.ys0  = ws + off; off += (size_t)SS * BB * HH;  // 2,097,152
  p.amv  = ws + off; off += 8192;
  p.ami  = (int*)(ws + off); off += 8192;
  size_t need_xg_bytes = (off + (size_t)SS * BB * G4) * 4 + 512;
  p.use_xg0 = (ws_size >= need_xg_bytes) ? 1 : 0;
  p.xg0  = ws + off;                               // 8,388,608 floats if used

  hipMemsetAsync(d_ws, 0, 256, stream);            // barrier state
  mega<<<dim3(GRID), dim3(BLK), 0, stream>>>(p);
}

// Round 3
// 34480.536 us; speedup vs baseline: 1.0951x; 1.0951x over previous
//
#include <hip/hip_runtime.h>

#define BB 32
#define SS 64
#define TT 64
#define VV 32000
#define EE 512
#define HH 1024
#define CHUNK 256
#define PADW 258
#define GRID 256
#define BLK 512
#define FLTMAX 3.402823466e38f

struct Par {
  const int *src, *tgt, *tmask;
  const float *enc_embed, *dec_embed;
  const float *enc_wih0, *enc_whh0, *enc_b0;
  const float *enc_wih1, *enc_whh1, *enc_b1;
  const float *dec_wih0, *dec_whh0, *dec_b0;
  const float *dec_wih1, *dec_whh1, *dec_b1;
  const float *fc_w, *fc_b;
  float *out;
  float *hA0, *hA1, *hB0, *hB1, *cA, *cB;
  float2 *cand;
  int *arr, *gen;
};

__device__ __forceinline__ float sigf(float x) { return 1.0f / (1.0f + expf(-x)); }

// ---------------------------------------------------------------------------
// grid barrier, contention-free: per-block arrival slots (release stores),
// block 0 polls all slots then publishes gen (release); others acquire-poll gen.
// All 256 blocks are co-resident (1 per CU). gen is monotonic -> no reset race.
// ---------------------------------------------------------------------------
__device__ __forceinline__ void gbar(int* arr, int* gen, int target) {
  __syncthreads();
  if (blockIdx.x == 0) {
    if (threadIdx.x < 64) {
      int s0 = threadIdx.x;
      for (;;) {
        int a0 = (s0 == 0) ? target
                           : __hip_atomic_load(arr + s0, __ATOMIC_ACQUIRE, __HIP_MEMORY_SCOPE_AGENT);
        int a1 = __hip_atomic_load(arr + s0 + 64,  __ATOMIC_ACQUIRE, __HIP_MEMORY_SCOPE_AGENT);
        int a2 = __hip_atomic_load(arr + s0 + 128, __ATOMIC_ACQUIRE, __HIP_MEMORY_SCOPE_AGENT);
        int a3 = __hip_atomic_load(arr + s0 + 192, __ATOMIC_ACQUIRE, __HIP_MEMORY_SCOPE_AGENT);
        bool mine = (a0 >= target) & (a1 >= target) & (a2 >= target) & (a3 >= target);
        if (__all(mine)) break;
        __builtin_amdgcn_s_sleep(1);
      }
    }
    __syncthreads();
    if (threadIdx.x == 0)
      __hip_atomic_store(gen, target, __ATOMIC_RELEASE, __HIP_MEMORY_SCOPE_AGENT);
  } else {
    if (threadIdx.x == 0) {
      __hip_atomic_store(arr + blockIdx.x, target, __ATOMIC_RELEASE, __HIP_MEMORY_SCOPE_AGENT);
      while (__hip_atomic_load(gen, __ATOMIC_ACQUIRE, __HIP_MEMORY_SCOPE_AGENT) < target)
        __builtin_amdgcn_s_sleep(4);
    }
    __syncthreads();
  }
}

// ---------------------------------------------------------------------------
// Fused LSTM layer phase. Block owns u0..u0+3 (16 gate-columns).
// Threads: b = tid&31, tc = tid>>5 (16 K-slices of 16 per 256-chunk).
// x read direct from global (embed table row via stok, or activation row).
// Cross-slice reduce via LDS, then cell for (b, u) on tid<128.
// ---------------------------------------------------------------------------
__device__ __forceinline__ void layer_phase(
    const float* __restrict__ xtab, const int* __restrict__ stok, int lenx,
    const float* __restrict__ hsrc,
    const float* __restrict__ wih, const float* __restrict__ whh,
    const float* __restrict__ bias,
    float* __restrict__ hdst, float* __restrict__ cbuf,
    float (*red)[16][33])
{
  const int tid = threadIdx.x;
  const int b = tid & 31, tc = tid >> 5;
  const int u0 = blockIdx.x * 4;

  float acc[16];
#pragma unroll
  for (int q = 0; q < 16; ++q) acc[q] = 0.f;

  // ---- x part ----
  {
    const float* xrow;
    bool xz = false;
    if (stok) { int tk = stok[b]; xz = (tk == 0); xrow = xtab + (long)tk * lenx; }
    else      { xrow = xtab + (long)b * lenx; }
    const float* xp = xrow + tc * 16;
    const float* wr[16];
#pragma unroll
    for (int q = 0; q < 16; ++q)
      wr[q] = wih + (long)((q >> 2) * HH + u0 + (q & 3)) * lenx + tc * 16;
    int nc = lenx >> 8;
    for (int c = 0; c < nc; ++c) {
      float4 x0, x1, x2, x3;
      if (xz) {
        x0 = make_float4(0.f,0.f,0.f,0.f); x1 = x0; x2 = x0; x3 = x0;
      } else {
        const float4* x4 = reinterpret_cast<const float4*>(xp);
        x0 = x4[0]; x1 = x4[1]; x2 = x4[2]; x3 = x4[3];
      }
      xp += 256;
#pragma unroll
      for (int q = 0; q < 16; ++q) {
        const float4* wp = reinterpret_cast<const float4*>(wr[q]);
        float4 w0 = wp[0], w1 = wp[1], w2 = wp[2], w3 = wp[3];
        acc[q] += x0.x*w0.x + x0.y*w0.y + x0.z*w0.z + x0.w*w0.w
                + x1.x*w1.x + x1.y*w1.y + x1.z*w1.z + x1.w*w1.w
                + x2.x*w2.x + x2.y*w2.y + x2.z*w2.z + x2.w*w2.w
                + x3.x*w3.x + x3.y*w3.y + x3.z*w3.z + x3.w*w3.w;
        wr[q] += 256;
      }
    }
  }
  // ---- h part (len HH) ----
  {
    const float* hp = hsrc + (long)b * HH + tc * 16;
    const float* wr[16];
#pragma unroll
    for (int q = 0; q < 16; ++q)
      wr[q] = whh + (long)((q >> 2) * HH + u0 + (q & 3)) * HH + tc * 16;
    for (int c = 0; c < 4; ++c) {
      const float4* x4 = reinterpret_cast<const float4*>(hp);
      float4 x0 = x4[0], x1 = x4[1], x2 = x4[2], x3 = x4[3];
      hp += 256;
#pragma unroll
      for (int q = 0; q < 16; ++q) {
        const float4* wp = reinterpret_cast<const float4*>(wr[q]);
        float4 w0 = wp[0], w1 = wp[1], w2 = wp[2], w3 = wp[3];
        acc[q] += x0.x*w0.x + x0.y*w0.y + x0.z*w0.z + x0.w*w0.w
                + x1.x*w1.x + x1.y*w1.y + x1.z*w1.z + x1.w*w1.w
                + x2.x*w2.x + x2.y*w2.y + x2.z*w2.z + x2.w*w2.w
                + x3.x*w3.x + x3.y*w3.y + x3.z*w3.z + x3.w*w3.w;
        wr[q] += 256;
      }
    }
  }
  // ---- reduce across tc + cell ----
#pragma unroll
  for (int q = 0; q < 16; ++q) red[tc][q][b] = acc[q];
  __syncthreads();
  if (tid < 128) {
    int bb = tid & 31, ul = tid >> 5;
    float g0 = bias[0*HH + u0 + ul], g1 = bias[1*HH + u0 + ul];
    float g2 = bias[2*HH + u0 + ul], g3 = bias[3*HH + u0 + ul];
#pragma unroll
    for (int t2 = 0; t2 < 16; ++t2) {
      g0 += red[t2][0*4 + ul][bb];
      g1 += red[t2][1*4 + ul][bb];
      g2 += red[t2][2*4 + ul][bb];
      g3 += red[t2][3*4 + ul][bb];
    }
    int iu = bb * HH + u0 + ul;
    float cn = sigf(g1) * cbuf[iu] + sigf(g0) * tanhf(g2);
    float hn = sigf(g3) * tanhf(cn);
    cbuf[iu] = cn;
    hdst[iu] = hn;
  }
}

// ---------------------------------------------------------------------------
__global__ __launch_bounds__(BLK, 1) void mega(Par p) {
  __shared__ float red[16][16][33];   // layer reduce; FC reuses as hs[32][258]
  __shared__ int   stok[32];
  __shared__ float sav[16][32];
  __shared__ int   sai[16][32];

  const int tid = threadIdx.x;
  const int bid = blockIdx.x;
  const int gid = bid * BLK + tid;
  int gen = 0;

  // ---- init: zero states (contiguous block of 6*32K floats), zero out[:,0,:]
  for (int i = gid; i < 6 * BB * HH; i += GRID * BLK) p.hA0[i] = 0.f;
  for (long g2 = gid; g2 < (long)BB * VV; g2 += (long)GRID * BLK) {
    int b = (int)(g2 / VV), v = (int)(g2 - (long)b * VV);
    p.out[(long)b * TT * VV + v] = 0.f;
  }
  gbar(p.arr, p.gen, ++gen);

  // ---- encoder: 64 steps x 2 phases
  for (int t = 0; t < SS; ++t) {
    float* hAr = (t & 1) ? p.hA1 : p.hA0;
    float* hAw = (t & 1) ? p.hA0 : p.hA1;
    float* hBr = (t & 1) ? p.hB1 : p.hB0;
    float* hBw = (t & 1) ? p.hB0 : p.hB1;
    if (tid < 32) stok[tid] = p.src[tid * SS + t];
    __syncthreads();
    layer_phase(p.enc_embed, stok, EE, hAr, p.enc_wih0, p.enc_whh0, p.enc_b0,
                hAw, p.cA, red);
    gbar(p.arr, p.gen, ++gen);
    layer_phase(hAw, nullptr, HH, hBr, p.enc_wih1, p.enc_whh1, p.enc_b1,
                hBw, p.cB, red);
    gbar(p.arr, p.gen, ++gen);
  }

  // ---- decoder: 63 steps x 3 phases (AM folded into L0)
  for (int k = 0; k < TT - 1; ++k) {
    // build input tokens for this step
    if (k == 0) {
      if (tid < 32) stok[tid] = p.tgt[tid * TT];
    } else {
      int b2 = tid & 31, grp = tid >> 5;
      float bv = -FLTMAX; int bi = 0x7fffffff;
      for (int s = grp; s < 250; s += 16) {
        float2 cv = p.cand[s * BB + b2];
        int ci = __float_as_int(cv.y);
        if (cv.x > bv || (cv.x == bv && ci < bi)) { bv = cv.x; bi = ci; }
      }
      sav[grp][b2] = bv; sai[grp][b2] = bi;
      __syncthreads();
      if (tid < 32) {
        float v = sav[0][tid]; int vi = sai[0][tid];
#pragma unroll
        for (int s = 1; s < 16; ++s) {
          float w = sav[s][tid]; int wi = sai[s][tid];
          if (w > v || (w == v && wi < vi)) { v = w; vi = wi; }
        }
        stok[tid] = (p.tmask[k] > 0) ? p.tgt[tid * TT + k] : vi;
      }
    }
    __syncthreads();

    float* hAr = (k & 1) ? p.hA1 : p.hA0;
    float* hAw = (k & 1) ? p.hA0 : p.hA1;
    float* hBr = (k & 1) ? p.hB1 : p.hB0;
    float* hBw = (k & 1) ? p.hB0 : p.hB1;

    layer_phase(p.dec_embed, stok, EE, hAr, p.dec_wih0, p.dec_whh0, p.dec_b0,
                hAw, p.cA, red);
    gbar(p.arr, p.gen, ++gen);
    layer_phase(hAw, nullptr, HH, hBr, p.dec_wih1, p.dec_whh1, p.dec_b1,
                hBw, p.cB, red);
    gbar(p.arr, p.gen, ++gen);

    // ---- FC phase: 250 blocks, 128 j each; logits row t=k+1 + tile argmax
    {
      int t = k + 1;
      if (bid < 250) {
        float (*hsFC)[PADW] = reinterpret_cast<float (*)[PADW]>(&red[0][0][0]);
        int lane = tid & 63, wid = tid >> 6, rb = lane & 31, hf = lane >> 5;
        int jbase = bid * 128 + wid * 16 + hf * 8;
        float af[8] = {0.f,0.f,0.f,0.f,0.f,0.f,0.f,0.f};
        for (int r = 0; r < 4; ++r) {
          __syncthreads();
          {
            int sb = tid >> 4, c0 = (tid & 15) << 4;
            const float4* s4 = reinterpret_cast<const float4*>(hBw + sb * HH + r * CHUNK + c0);
            float4 v0 = s4[0], v1 = s4[1], v2 = s4[2], v3 = s4[3];
            float* dd = &hsFC[sb][c0];
            dd[0]=v0.x; dd[1]=v0.y; dd[2]=v0.z; dd[3]=v0.w;
            dd[4]=v1.x; dd[5]=v1.y; dd[6]=v1.z; dd[7]=v1.w;
            dd[8]=v2.x; dd[9]=v2.y; dd[10]=v2.z; dd[11]=v2.w;
            dd[12]=v3.x; dd[13]=v3.y; dd[14]=v3.z; dd[15]=v3.w;
          }
          __syncthreads();
          const float* wr8[8];
#pragma unroll
          for (int q = 0; q < 8; ++q)
            wr8[q] = p.fc_w + (long)(jbase + q) * HH + r * CHUNK;
#pragma unroll 2
          for (int kk = 0; kk < CHUNK; kk += 4) {
            float2 h01 = *reinterpret_cast<const float2*>(&hsFC[rb][kk]);
            float2 h23 = *reinterpret_cast<const float2*>(&hsFC[rb][kk + 2]);
#pragma unroll
            for (int q = 0; q < 8; ++q) {
              float4 w4 = *reinterpret_cast<const float4*>(wr8[q] + kk);
              af[q] += h01.x*w4.x + h01.y*w4.y + h23.x*w4.z + h23.y*w4.w;
            }
          }
        }
        float bv = -FLTMAX; int bi = 0;
        float* dst = p.out + (long)rb * TT * VV + (long)t * VV + jbase;
#pragma unroll
        for (int q = 0; q < 8; ++q) {
          float v = af[q] + p.fc_b[jbase + q];
          dst[q] = v;
          if (v > bv) { bv = v; bi = jbase + q; }
        }
        __syncthreads();
        sav[wid * 2 + hf][rb] = bv; sai[wid * 2 + hf][rb] = bi;
        __syncthreads();
        if (tid < 32) {
          float v = sav[0][tid]; int vi = sai[0][tid];
#pragma unroll
          for (int s = 1; s < 16; ++s) {
            float w = sav[s][tid]; int wi = sai[s][tid];
            if (w > v || (w == v && wi < vi)) { v = w; vi = wi; }
          }
          p.cand[bid * BB + tid] = make_float2(v, __int_as_float(vi));
        }
      }
      gbar(p.arr, p.gen, ++gen);
    }
  }
}

// ---------------------------------------------------------------------------
extern "C" void kernel_launch(void* const* d_in, const int* in_sizes, int n_in,
                              void* d_out, int out_size, void* d_ws, size_t ws_size,
                              hipStream_t stream) {
  Par p;
  p.src       = (const int*)d_in[0];
  p.tgt       = (const int*)d_in[1];
  p.tmask     = (const int*)d_in[2];
  p.enc_embed = (const float*)d_in[3];
  p.dec_embed = (const float*)d_in[4];
  p.enc_wih0  = (const float*)d_in[5];
  p.enc_whh0  = (const float*)d_in[6];
  p.enc_b0    = (const float*)d_in[7];
  p.enc_wih1  = (const float*)d_in[8];
  p.enc_whh1  = (const float*)d_in[9];
  p.enc_b1    = (const float*)d_in[10];
  p.dec_wih0  = (const float*)d_in[11];
  p.dec_whh0  = (const float*)d_in[12];
  p.dec_b0    = (const float*)d_in[13];
  p.dec_wih1  = (const float*)d_in[14];
  p.dec_whh1  = (const float*)d_in[15];
  p.dec_b1    = (const float*)d_in[16];
  p.fc_w      = (const float*)d_in[17];
  p.fc_b      = (const float*)d_in[18];
  p.out       = (float*)d_out;

  p.arr = (int*)d_ws;                  // 256 ints
  p.gen = (int*)d_ws + 320;            // own region, within 2KB memset
  float* f = (float*)((char*)d_ws + 2048);
  p.hA0 = f; f += BB * HH;
  p.hA1 = f; f += BB * HH;
  p.hB0 = f; f += BB * HH;
  p.hB1 = f; f += BB * HH;
  p.cA  = f; f += BB * HH;
  p.cB  = f; f += BB * HH;
  p.cand = (float2*)f;                 // 250*32 float2

  hipMemsetAsync(d_ws, 0, 2048, stream);
  mega<<<dim3(GRID), dim3(BLK), 0, stream>>>(p);
}

// Round 4
// 23441.350 us; speedup vs baseline: 1.6108x; 1.4709x over previous
//
#include <hip/hip_runtime.h>

#define BB 32
#define SS 64
#define TT 64
#define VV 32000
#define EE 512
#define HH 1024
#define CHUNK 256
#define PADW 258
#define GRID 256
#define BLK 512
#define FLTMAX 3.402823466e38f

typedef unsigned long long u64;

struct Par {
  const int *src, *tgt, *tmask;
  const float *enc_embed, *dec_embed;
  const float *enc_wih0, *enc_whh0, *enc_b0;
  const float *enc_wih1, *enc_whh1, *enc_b1;
  const float *dec_wih0, *dec_whh0, *dec_b0;
  const float *dec_wih1, *dec_whh1, *dec_b1;
  const float *fc_w, *fc_b;
  float *out;
  float *hA0, *hA1, *hB0, *hB1;   // cross-block state: coherent access only
  float *cA, *cB;                 // [256][128] block-private, cacheline-exclusive
  float2 *cand;
  int *arr; int *gen;
};

__device__ __forceinline__ float sigf(float x) { return 1.0f / (1.0f + expf(-x)); }

// ---- coherent (agent-scope, RELAXED: no cache-invalidate fences) access ----
__device__ __forceinline__ float2 ldc2(const float* p) {
  u64 v = __hip_atomic_load((const u64*)p, __ATOMIC_RELAXED, __HIP_MEMORY_SCOPE_AGENT);
  union { u64 u; float2 f; } c; c.u = v; return c.f;
}
__device__ __forceinline__ void stc2(float* p, float x, float y) {
  union { u64 u; float2 f; } c; c.f = make_float2(x, y);
  __hip_atomic_store((u64*)p, c.u, __ATOMIC_RELAXED, __HIP_MEMORY_SCOPE_AGENT);
}
__device__ __forceinline__ void stc1(float* p, float x) {
  __hip_atomic_store(p, x, __ATOMIC_RELAXED, __HIP_MEMORY_SCOPE_AGENT);
}

// ---------------------------------------------------------------------------
// Fence-free grid barrier. All shared data moves via write-through coherent
// stores, so visibility only needs vmcnt(0) before the arrival signal —
// no buffer_inv / buffer_wbl2 (those flash the whole per-XCD L2).
// ---------------------------------------------------------------------------
__device__ __forceinline__ void gbar(int* arr, int* gen, int target) {
  __syncthreads();
  asm volatile("s_waitcnt vmcnt(0)" ::: "memory");
  if (blockIdx.x == 0) {
    if (threadIdx.x < 64) {
      int s = threadIdx.x;
      for (;;) {
        int a0 = (s == 0) ? target
                          : __hip_atomic_load(arr + s, __ATOMIC_RELAXED, __HIP_MEMORY_SCOPE_AGENT);
        int a1 = __hip_atomic_load(arr + s + 64,  __ATOMIC_RELAXED, __HIP_MEMORY_SCOPE_AGENT);
        int a2 = __hip_atomic_load(arr + s + 128, __ATOMIC_RELAXED, __HIP_MEMORY_SCOPE_AGENT);
        int a3 = __hip_atomic_load(arr + s + 192, __ATOMIC_RELAXED, __HIP_MEMORY_SCOPE_AGENT);
        if (__all((a0 >= target) & (a1 >= target) & (a2 >= target) & (a3 >= target))) break;
        __builtin_amdgcn_s_sleep(1);
      }
    }
    __syncthreads();
    if (threadIdx.x == 0)
      __hip_atomic_store(gen, target, __ATOMIC_RELAXED, __HIP_MEMORY_SCOPE_AGENT);
  } else {
    if (threadIdx.x == 0) {
      __hip_atomic_store(arr + blockIdx.x, target, __ATOMIC_RELAXED, __HIP_MEMORY_SCOPE_AGENT);
      while (__hip_atomic_load(gen, __ATOMIC_RELAXED, __HIP_MEMORY_SCOPE_AGENT) < target)
        __builtin_amdgcn_s_sleep(1);
    }
    __syncthreads();
  }
  asm volatile("" ::: "memory");
}

// ---------------------------------------------------------------------------
// One LSTM layer step slice: block owns u0..u0+3 (16 gate-cols).
// Threads (b=tid&31, tc=tid>>5). Weights: plain cached loads (stay in L2).
// x: embed table (plain, via stok) or coherent h buffer. h: coherent.
// ---------------------------------------------------------------------------
__device__ __forceinline__ void lstm_sub(
    const float* __restrict__ xembed, const int* stokLDS,
    const float* __restrict__ xcoh, int lenx,
    const float* __restrict__ hsrc,
    const float* __restrict__ wih, const float* __restrict__ whh,
    const float* __restrict__ bias,
    float* __restrict__ hdst, float* __restrict__ cpriv,
    float (*red)[16][33])
{
  const int tid = threadIdx.x;
  const int b = tid & 31, tc = tid >> 5;
  const int u0 = blockIdx.x * 4;
  float acc[16];
#pragma unroll
  for (int q = 0; q < 16; ++q) acc[q] = 0.f;
  float xr[16];

  const int ncx = lenx >> 8;
  for (int c = 0; c < ncx; ++c) {
    const int col = c * CHUNK + tc * 16;
    if (xembed) {
      int tk = stokLDS[b];
      if (tk) {
        const float4* s4 = reinterpret_cast<const float4*>(xembed + (size_t)tk * lenx + col);
#pragma unroll
        for (int e = 0; e < 4; ++e) {
          float4 v = s4[e];
          xr[e*4+0]=v.x; xr[e*4+1]=v.y; xr[e*4+2]=v.z; xr[e*4+3]=v.w;
        }
      } else {
#pragma unroll
        for (int e = 0; e < 16; ++e) xr[e] = 0.f;
      }
    } else {
#pragma unroll
      for (int e = 0; e < 8; ++e) {
        float2 v = ldc2(xcoh + (size_t)b * lenx + col + e * 2);
        xr[e*2] = v.x; xr[e*2+1] = v.y;
      }
    }
#pragma unroll
    for (int q = 0; q < 16; ++q) {
      const float4* w4 = reinterpret_cast<const float4*>(
          wih + (size_t)((q >> 2) * HH + u0 + (q & 3)) * lenx + col);
      float4 w0 = w4[0], w1 = w4[1], w2 = w4[2], w3 = w4[3];
      acc[q] += xr[0]*w0.x + xr[1]*w0.y + xr[2]*w0.z + xr[3]*w0.w
              + xr[4]*w1.x + xr[5]*w1.y + xr[6]*w1.z + xr[7]*w1.w
              + xr[8]*w2.x + xr[9]*w2.y + xr[10]*w2.z + xr[11]*w2.w
              + xr[12]*w3.x + xr[13]*w3.y + xr[14]*w3.z + xr[15]*w3.w;
    }
  }
  for (int c = 0; c < 4; ++c) {
    const int col = c * CHUNK + tc * 16;
#pragma unroll
    for (int e = 0; e < 8; ++e) {
      float2 v = ldc2(hsrc + (size_t)b * HH + col + e * 2);
      xr[e*2] = v.x; xr[e*2+1] = v.y;
    }
#pragma unroll
    for (int q = 0; q < 16; ++q) {
      const float4* w4 = reinterpret_cast<const float4*>(
          whh + (size_t)((q >> 2) * HH + u0 + (q & 3)) * HH + col);
      float4 w0 = w4[0], w1 = w4[1], w2 = w4[2], w3 = w4[3];
      acc[q] += xr[0]*w0.x + xr[1]*w0.y + xr[2]*w0.z + xr[3]*w0.w
              + xr[4]*w1.x + xr[5]*w1.y + xr[6]*w1.z + xr[7]*w1.w
              + xr[8]*w2.x + xr[9]*w2.y + xr[10]*w2.z + xr[11]*w2.w
              + xr[12]*w3.x + xr[13]*w3.y + xr[14]*w3.z + xr[15]*w3.w;
    }
  }
#pragma unroll
  for (int q = 0; q < 16; ++q) red[tc][q][b] = acc[q];
  __syncthreads();
  if (tid < 128) {
    int bb = tid & 31, ul = tid >> 5;
    float g0 = bias[0*HH + u0 + ul], g1 = bias[1*HH + u0 + ul];
    float g2 = bias[2*HH + u0 + ul], g3 = bias[3*HH + u0 + ul];
#pragma unroll
    for (int t2 = 0; t2 < 16; ++t2) {
      g0 += red[t2][0*4 + ul][bb];
      g1 += red[t2][1*4 + ul][bb];
      g2 += red[t2][2*4 + ul][bb];
      g3 += red[t2][3*4 + ul][bb];
    }
    int ci = bb * 4 + ul;                    // block-private c slot
    float cn = sigf(g1) * cpriv[ci] + sigf(g0) * tanhf(g2);
    float hn = sigf(g3) * tanhf(cn);
    cpriv[ci] = cn;
    stc1(hdst + (size_t)bb * HH + u0 + ul, hn);
  }
  __syncthreads();
}

// ---------------------------------------------------------------------------
__global__ __launch_bounds__(BLK, 1) void mega(Par p) {
  __shared__ float red[16][16][33];
  __shared__ int   stok[32];
  __shared__ float sav[16][32];
  __shared__ int   sai[16][32];

  const int tid = threadIdx.x;
  const int bid = blockIdx.x;
  const int gid = bid * BLK + tid;
  int gen = 0;

  float* cApriv = p.cA + bid * 128;
  float* cBpriv = p.cB + bid * 128;

  // ---- init
  for (int i = gid * 2; i < 4 * BB * HH; i += GRID * BLK * 2)
    stc2(p.hA0 + i, 0.f, 0.f);                       // hA0,hA1,hB0,hB1 contiguous
  if (tid < 128) { cApriv[tid] = 0.f; cBpriv[tid] = 0.f; }
  for (long g2 = gid; g2 < (long)BB * VV; g2 += (long)GRID * BLK) {
    int b = (int)(g2 / VV), v = (int)(g2 - (long)b * VV);
    __builtin_nontemporal_store(0.f, p.out + (size_t)b * TT * VV + v);
  }
  gbar(p.arr, p.gen, ++gen);

  // ---- encoder: merged L0(tt) || L1(tt-1), one barrier per phase
  for (int tt = 0; tt <= SS; ++tt) {
    if (tid < 32 && tt < SS) stok[tid] = p.src[tid * SS + tt];
    __syncthreads();
    float* hAev = (tt & 1) ? p.hA1 : p.hA0;   // A[tt&1]     : L0 write
    float* hAod = (tt & 1) ? p.hA0 : p.hA1;   // A[(tt+1)&1] : L0 h-read, L1 x-read
    float* hBev = (tt & 1) ? p.hB1 : p.hB0;   // B[tt&1]     : L1 h-read
    float* hBod = (tt & 1) ? p.hB0 : p.hB1;   // B[(tt+1)&1] : L1 write
    if (tt < SS)
      lstm_sub(p.enc_embed, stok, nullptr, EE, hAod,
               p.enc_wih0, p.enc_whh0, p.enc_b0, hAev, cApriv, red);
    if (tt >= 1)
      lstm_sub(nullptr, nullptr, hAod, HH, hBev,
               p.enc_wih1, p.enc_whh1, p.enc_b1, hBod, cBpriv, red);
    gbar(p.arr, p.gen, ++gen);
  }

  // ---- decoder
  for (int k = 0; k < TT - 1; ++k) {
    // build step-k input tokens (redundantly per block)
    if (k == 0) {
      if (tid < 32) stok[tid] = p.tgt[tid * TT];
    } else {
      int b2 = tid & 31, grp = tid >> 5;
      float bv = -FLTMAX; int bi = 0x7fffffff;
      for (int s = grp; s < 250; s += 16) {
        float2 cv = ldc2((const float*)&p.cand[s * BB + b2]);
        int ci = __float_as_int(cv.y);
        if (cv.x > bv || (cv.x == bv && ci < bi)) { bv = cv.x; bi = ci; }
      }
      sav[grp][b2] = bv; sai[grp][b2] = bi;
      __syncthreads();
      if (tid < 32) {
        float v = sav[0][tid]; int vi = sai[0][tid];
#pragma unroll
        for (int s = 1; s < 16; ++s) {
          float w = sav[s][tid]; int wi = sai[s][tid];
          if (w > v || (w == v && wi < vi)) { v = w; vi = wi; }
        }
        stok[tid] = (p.tmask[k] > 0) ? p.tgt[tid * TT + k] : vi;
      }
    }
    __syncthreads();

    float* hAw = (k & 1) ? p.hA1 : p.hA0;
    float* hAr = (k & 1) ? p.hA0 : p.hA1;
    float* hBw = (k & 1) ? p.hB1 : p.hB0;
    float* hBr = (k & 1) ? p.hB0 : p.hB1;

    lstm_sub(p.dec_embed, stok, nullptr, EE, hAr,
             p.dec_wih0, p.dec_whh0, p.dec_b0, hAw, cApriv, red);
    gbar(p.arr, p.gen, ++gen);
    lstm_sub(nullptr, nullptr, hAw, HH, hBr,
             p.dec_wih1, p.dec_whh1, p.dec_b1, hBw, cBpriv, red);
    gbar(p.arr, p.gen, ++gen);

    // ---- FC: blocks 0..249, 128 j each; logits t=k+1 + per-tile argmax
    if (bid < 250) {
      int t = k + 1;
      float (*hsFC)[PADW] = reinterpret_cast<float (*)[PADW]>(&red[0][0][0]);
      int lane = tid & 63, wid = tid >> 6, rb = lane & 31, hf = lane >> 5;
      int jbase = bid * 128 + wid * 16 + hf * 8;
      float af[8] = {0.f,0.f,0.f,0.f,0.f,0.f,0.f,0.f};
      for (int r = 0; r < 4; ++r) {
        __syncthreads();
        {
          int sb = tid >> 4, c0 = (tid & 15) << 4;
          const float* srcp = hBw + (size_t)sb * HH + r * CHUNK + c0;
          float* dd = &hsFC[sb][c0];
#pragma unroll
          for (int e = 0; e < 8; ++e) {
            float2 v = ldc2(srcp + e * 2);
            dd[e*2] = v.x; dd[e*2+1] = v.y;
          }
        }
        __syncthreads();
        const float* wr8[8];
#pragma unroll
        for (int q = 0; q < 8; ++q)
          wr8[q] = p.fc_w + (size_t)(jbase + q) * HH + r * CHUNK;
#pragma unroll 2
        for (int kk = 0; kk < CHUNK; kk += 4) {
          float2 h01 = *reinterpret_cast<const float2*>(&hsFC[rb][kk]);
          float2 h23 = *reinterpret_cast<const float2*>(&hsFC[rb][kk + 2]);
#pragma unroll
          for (int q = 0; q < 8; ++q) {
            float4 w4 = *reinterpret_cast<const float4*>(wr8[q] + kk);
            af[q] += h01.x*w4.x + h01.y*w4.y + h23.x*w4.z + h23.y*w4.w;
          }
        }
      }
      float bv = -FLTMAX; int bi = 0;
      float* dst = p.out + (size_t)rb * TT * VV + (size_t)t * VV + jbase;
#pragma unroll
      for (int q = 0; q < 8; ++q) {
        float v = af[q] + p.fc_b[jbase + q];
        __builtin_nontemporal_store(v, dst + q);
        if (v > bv) { bv = v; bi = jbase + q; }
      }
      __syncthreads();
      sav[wid * 2 + hf][rb] = bv; sai[wid * 2 + hf][rb] = bi;
      __syncthreads();
      if (tid < 32) {
        float v = sav[0][tid]; int vi = sai[0][tid];
#pragma unroll
        for (int s = 1; s < 16; ++s) {
          float w = sav[s][tid]; int wi = sai[s][tid];
          if (w > v || (w == v && wi < vi)) { v = w; vi = wi; }
        }
        stc2((float*)&p.cand[bid * BB + tid], v, __int_as_float(vi));
      }
    }
    gbar(p.arr, p.gen, ++gen);
  }
}

// ---------------------------------------------------------------------------
extern "C" void kernel_launch(void* const* d_in, const int* in_sizes, int n_in,
                              void* d_out, int out_size, void* d_ws, size_t ws_size,
                              hipStream_t stream) {
  Par p;
  p.src       = (const int*)d_in[0];
  p.tgt       = (const int*)d_in[1];
  p.tmask     = (const int*)d_in[2];
  p.enc_embed = (const float*)d_in[3];
  p.dec_embed = (const float*)d_in[4];
  p.enc_wih0  = (const float*)d_in[5];
  p.enc_whh0  = (const float*)d_in[6];
  p.enc_b0    = (const float*)d_in[7];
  p.enc_wih1  = (const float*)d_in[8];
  p.enc_whh1  = (const float*)d_in[9];
  p.enc_b1    = (const float*)d_in[10];
  p.dec_wih0  = (const float*)d_in[11];
  p.dec_whh0  = (const float*)d_in[12];
  p.dec_b0    = (const float*)d_in[13];
  p.dec_wih1  = (const float*)d_in[14];
  p.dec_whh1  = (const float*)d_in[15];
  p.dec_b1    = (const float*)d_in[16];
  p.fc_w      = (const float*)d_in[17];
  p.fc_b      = (const float*)d_in[18];
  p.out       = (float*)d_out;

  p.arr = (int*)d_ws;                 // 256 ints
  p.gen = (int*)d_ws + 288;           // own cacheline, still inside memset
  float* f = (float*)((char*)d_ws + 4096);
  p.hA0 = f; f += BB * HH;            // keep hA0..hB1 contiguous (init loop)
  p.hA1 = f; f += BB * HH;
  p.hB0 = f; f += BB * HH;
  p.hB1 = f; f += BB * HH;
  p.cA  = f; f += GRID * 128;         // block-private, 512B per block
  p.cB  = f; f += GRID * 128;
  p.cand = (float2*)f;                // 250*32 float2

  hipMemsetAsync(d_ws, 0, 4096, stream);
  mega<<<dim3(GRID), dim3(BLK), 0, stream>>>(p);
}